// Round 9
// baseline (356.665 us; speedup 1.0000x reference)
//
#include <hip/hip_runtime.h>
#include <cmath>

// ---------------------------------------------------------------------------
// WireframeDetector: NMS -> top-k 300 junctions -> line sampling (bilinear +
// maxpool) -> 3-layer MLP (fp16 MFMA for the two 1024x1024 GEMMs).
// R9: true double-buffered K-loop — partial s_waitcnt vmcnt(4) + raw
//     s_barrier (no compiler vmcnt(0) drain): staging latency hidden behind
//     the previous tile's 16 MFMAs instead of serially exposed per round.
//     out-zeroing folded into preproc (one less dispatch).
// ---------------------------------------------------------------------------

typedef _Float16 f16;
typedef _Float16 f16x2 __attribute__((ext_vector_type(2)));
typedef _Float16 f16x8 __attribute__((ext_vector_type(8)));
typedef float f32x4 __attribute__((ext_vector_type(4)));

#define HWD 128
#define NPIX 16384            // 128*128
#define TOPK_N 300
#define NLINES 20000
#define MPAD 20096            // 157 * 128
#define KDIM 1024
#define NDIM 1024
#define MAXCAND 4096

// async global->LDS, 16B per lane; LDS dest = wave-uniform base + lane*16
#define G2L(gp, lp) __builtin_amdgcn_global_load_lds( \
    (const __attribute__((address_space(1))) void*)(gp), \
    (__attribute__((address_space(3))) void*)(lp), 16, 0, 0)

// ---------------------------------------------------------------------------
// Fused preprocessing, one dispatch of 764 blocks:
//   blocks 0..127   : transpose loi [C][H][W] fp32 -> loiT [H][W][C] fp16
//   blocks 128..639 : transpose W1/W2 [K][N] fp32 -> [N][K] fp16
//   blocks 640..703 : 3x3 NMS on jloc, survivors -> cand list (count pre-zeroed)
//   blocks 704..763 : zero out[60000] (consumed by gemm2's atomicAdd epilogue)
// ---------------------------------------------------------------------------
__global__ __launch_bounds__(256) void preproc_kernel(
    const float* __restrict__ loi, f16* __restrict__ loiT,
    const float* __restrict__ W1, f16* __restrict__ W1T,
    const float* __restrict__ W2, f16* __restrict__ W2T,
    const float* __restrict__ jloc, unsigned long long* __restrict__ cand,
    int* __restrict__ count, float* __restrict__ out, int out_n)
{
    const int bid = blockIdx.x;
    const int tid = threadIdx.x;
    if (bid < 128) {
        __shared__ f16 t[128 * 130];     // [x][c], +2 pad kills bank conflicts
        const int y = bid;
        #pragma unroll 4
        for (int it = 0; it < 64; ++it) {
            int idx = it * 256 + tid;    // c-major, x fast -> coalesced read
            int c = idx >> 7, x = idx & 127;
            t[x * 130 + c] = (f16)loi[c * NPIX + y * HWD + x];
        }
        __syncthreads();
        #pragma unroll
        for (int it = 0; it < 8; ++it) {
            int j = it * 256 + tid;      // 2048 chunks of 8 f16
            int x = j >> 4, cc = (j & 15) * 8;
            f16x8 v;
            #pragma unroll
            for (int u = 0; u < 8; ++u) v[u] = t[x * 130 + cc + u];
            *(f16x8*)(loiT + (y * HWD + x) * HWD + cc) = v;
        }
    } else if (bid < 640) {
        const int b = bid - 128;         // 0..511
        const float* W = (b < 256) ? W1 : W2;
        f16* Wt = (b < 256) ? W1T : W2T;
        const int bb = b & 255;
        __shared__ f16 t[64 * 66];
        const int k0 = (bb >> 4) * 64;
        const int n0 = (bb & 15) * 64;
        #pragma unroll 4
        for (int it = 0; it < 16; ++it) {
            int i = it * 256 + tid;      // coalesced read over n
            int r = i >> 6, c = i & 63;
            t[c * 66 + r] = (f16)W[(size_t)(k0 + r) * NDIM + n0 + c];
        }
        __syncthreads();
        #pragma unroll
        for (int it = 0; it < 2; ++it) {
            int j = it * 256 + tid;
            int nr = j >> 3, kc = (j & 7) * 8;
            f16x8 v;
            #pragma unroll
            for (int u = 0; u < 8; ++u) v[u] = t[nr * 66 + kc + u];
            *(f16x8*)(Wt + (size_t)(n0 + nr) * KDIM + k0 + kc) = v;
        }
    } else if (bid < 704) {
        const int p = (bid - 640) * 256 + tid;   // 64 blocks x 256 = 16384
        const int y = p >> 7, x = p & 127;
        const float c = jloc[p];
        float m = c;
        for (int dy = -1; dy <= 1; ++dy) {
            int yy = y + dy;
            if (yy < 0 || yy >= HWD) continue;
            for (int dx = -1; dx <= 1; ++dx) {
                int xx = x + dx;
                if (xx < 0 || xx >= HWD) continue;
                m = fmaxf(m, jloc[yy * HWD + xx]);
            }
        }
        if (c == m && c > 0.0f) {
            int pos = atomicAdd(count, 1);
            if (pos < MAXCAND) {
                unsigned int ub = __float_as_uint(c);
                cand[pos] = ((unsigned long long)ub << 32) |
                            (unsigned long long)(0xFFFFFFFFu - (unsigned int)p);
            }
        }
    } else {
        const int base = (bid - 704) * 1024 + tid * 4;   // 60 blocks cover 61440
        #pragma unroll
        for (int u = 0; u < 4; ++u)
            if (base + u < out_n) out[base + u] = 0.f;
    }
}

// ---------------------------------------------------------------------------
// Rank-select top-300, LDS-cached. Keys unique => ranks exact; matches
// jax.lax.top_k order (value desc, index asc).
// ---------------------------------------------------------------------------
__global__ __launch_bounds__(256) void rank_junc_kernel(
    const unsigned long long* __restrict__ cand, const int* __restrict__ count,
    const float* __restrict__ joff, float* __restrict__ juncs /* [300][2] */)
{
    __shared__ unsigned long long keys[MAXCAND];   // 32 KB
    const int n = min(*count, MAXCAND);
    const int t = blockIdx.x * 256 + threadIdx.x;  // 16 blocks = 4096 threads
    for (int i = threadIdx.x; i < n; i += 256)
        keys[i] = cand[i];
    __syncthreads();
    if (t >= n) return;
    const unsigned long long key = keys[t];
    int rank = 0;
    int j = 0;
    for (; j + 4 <= n; j += 4) {
        rank += (keys[j]     > key);
        rank += (keys[j + 1] > key);
        rank += (keys[j + 2] > key);
        rank += (keys[j + 3] > key);
    }
    for (; j < n; ++j) rank += (keys[j] > key);
    if (rank < TOPK_N) {
        unsigned int p = 0xFFFFFFFFu - (unsigned int)(key & 0xFFFFFFFFull);
        // x = idx%w + (sigmoid(joff0)-0.5) + 0.5 = idx%w + sigmoid(joff0)
        float sx = 1.0f / (1.0f + expf(-joff[p]));
        float sy = 1.0f / (1.0f + expf(-joff[NPIX + p]));
        juncs[2 * rank + 0] = (float)(p & 127) + sx;
        juncs[2 * rank + 1] = (float)(p >> 7) + sy;
    }
}

// ---------------------------------------------------------------------------
// Per-line sampling: 32 pts bilinear over loiT[H][W][C], maxpool groups of 4,
// write fp16 feats row. 4 lines/block; lane owns channels 2*lane, 2*lane+1.
// ---------------------------------------------------------------------------
__global__ __launch_bounds__(256) void sample_kernel(
    const f16* __restrict__ loiT, const float* __restrict__ juncs,
    const int* __restrict__ edge_idx, f16* __restrict__ feats)
{
    const int l = blockIdx.x * 4 + (threadIdx.x >> 6);
    const int lane = threadIdx.x & 63;
    const int e0 = edge_idx[2 * l], e1 = edge_idx[2 * l + 1];
    const float ux = juncs[2 * e0], uy = juncs[2 * e0 + 1];
    const float vx = juncs[2 * e1], vy = juncs[2 * e1 + 1];
    const int c2 = lane * 2;

    f16x8 o0, o1;
    #pragma unroll
    for (int p = 0; p < 8; ++p) {
        float m0 = -INFINITY, m1 = -INFINITY;
        #pragma unroll
        for (int jj = 0; jj < 4; ++jj) {
            const int j = p * 4 + jj;
            const float t = (float)j * (1.0f / 31.0f);
            const float px = ux * t + vx * (1.0f - t) - 0.5f;
            const float py = uy * t + vy * (1.0f - t) - 0.5f;
            float fx0 = fminf(fmaxf(floorf(px), 0.0f), 127.0f);
            float fy0 = fminf(fmaxf(floorf(py), 0.0f), 127.0f);
            float fx1 = fminf(fx0 + 1.0f, 127.0f);
            float fy1 = fminf(fy0 + 1.0f, 127.0f);
            int ix0 = (int)fx0, iy0 = (int)fy0, ix1 = (int)fx1, iy1 = (int)fy1;
            float w00 = (fy1 - py) * (fx1 - px);
            float w10 = (py - fy0) * (fx1 - px);
            float w01 = (fy1 - py) * (px - fx0);
            float w11 = (py - fy0) * (px - fx0);
            f16x2 v00 = *(const f16x2*)(loiT + (iy0 * HWD + ix0) * HWD + c2);
            f16x2 v10 = *(const f16x2*)(loiT + (iy1 * HWD + ix0) * HWD + c2);
            f16x2 v01 = *(const f16x2*)(loiT + (iy0 * HWD + ix1) * HWD + c2);
            f16x2 v11 = *(const f16x2*)(loiT + (iy1 * HWD + ix1) * HWD + c2);
            float s0 = (float)v00.x * w00 + (float)v10.x * w10 +
                       (float)v01.x * w01 + (float)v11.x * w11;
            float s1 = (float)v00.y * w00 + (float)v10.y * w10 +
                       (float)v01.y * w01 + (float)v11.y * w11;
            m0 = fmaxf(m0, s0);
            m1 = fmaxf(m1, s1);
        }
        o0[p] = (f16)m0;   // channel c2   -> feats[l, 16*lane + p]
        o1[p] = (f16)m1;   // channel c2+1 -> feats[l, 16*lane + 8 + p]
    }
    f16* dst = feats + (size_t)l * KDIM + lane * 16;
    *(f16x8*)(dst) = o0;
    *(f16x8*)(dst + 8) = o1;
}

// ---------------------------------------------------------------------------
// GEMM: 128x128 tile, BK=32, 256 threads (2x2 waves of 64x64 subtiles),
// DOUBLE-BUFFERED: per stage each wave issues 4 G2L into buf[nxt], then
// s_waitcnt vmcnt(4) (cur's loads done, nxt's stay in flight) + raw
// s_barrier — no compiler-inserted vmcnt(0) drain. Second raw barrier after
// compute protects buf[nxt] overwrite. Natural 2D grid.
// head=0: C = relu(A@Bt^T + bias) stored fp16.
// head=1: v = relu(A@Bt^T + bias); out[m][j] += v . W3  (atomicAdd, + b3 once)
// ---------------------------------------------------------------------------
__global__ __launch_bounds__(256, 2) void gemm_bias_relu_kernel(
    const f16* __restrict__ A, const f16* __restrict__ Bt,
    const float* __restrict__ bias, f16* __restrict__ C,
    const float* __restrict__ W3, const float* __restrict__ b3,
    float* __restrict__ out, int K, int head)
{
    const int tid = threadIdx.x;
    const int wave = tid >> 6, lane = tid & 63;
    const int wm = wave >> 1, wn = wave & 1;
    const int m0 = blockIdx.x * 128;
    const int n0 = blockIdx.y * 128;
    const int N = NDIM;

    __shared__ f16 sA[2][128 * 32];
    __shared__ f16 sB[2][128 * 32];

    f32x4 acc[4][4];
    #pragma unroll
    for (int mi = 0; mi < 4; ++mi)
        #pragma unroll
        for (int ni = 0; ni < 4; ++ni)
            acc[mi][ni] = (f32x4){0.f, 0.f, 0.f, 0.f};

    // DMA staging (per 8KB buffer): 8 segs of 1KB (16 rows x 64B). Wave w
    // owns segs {w, w+4}. Lane i: row seg*16 + (i>>2), 16B chunk i&3 ->
    // monotonic per-lane addresses (DMA-coalescing-safe).
    const int rs0 = wave * 16 + (lane >> 2);
    const int rs1 = rs0 + 64;
    const int kc = (lane & 3) * 8;
    const f16* gA0 = A + (size_t)(m0 + rs0) * K + kc;
    const f16* gA1 = A + (size_t)(m0 + rs1) * K + kc;
    const f16* gB0 = Bt + (size_t)(n0 + rs0) * K + kc;
    const f16* gB1 = Bt + (size_t)(n0 + rs1) * K + kc;
    const int so0 = wave * 512;               // + lane*16B implicit
    const int so1 = (wave + 4) * 512;

    const int col16 = lane & 15;
    const int kq = (lane >> 4) * 8;

    // prologue: stage K-tile 0 into buf 0 (4 loads in flight)
    G2L(gA0, sA[0] + so0);
    G2L(gA1, sA[0] + so1);
    G2L(gB0, sB[0] + so0);
    G2L(gB1, sB[0] + so1);

    #pragma unroll 2
    for (int k0 = 0; k0 < K; k0 += 32) {
        const int cur = (k0 >> 5) & 1;
        const int nxt = cur ^ 1;
        if (k0 + 32 < K) {
            G2L(gA0 + k0 + 32, sA[nxt] + so0);   // 8 outstanding
            G2L(gA1 + k0 + 32, sA[nxt] + so1);
            G2L(gB0 + k0 + 32, sB[nxt] + so0);
            G2L(gB1 + k0 + 32, sB[nxt] + so1);
            __builtin_amdgcn_s_waitcnt(0x0f74);  // vmcnt(4): cur done, nxt in flight
        } else {
            __builtin_amdgcn_s_waitcnt(0x0f70);  // vmcnt(0): last tile
        }
        __builtin_amdgcn_s_barrier();            // all waves' cur writes landed

        const f16* sAc = sA[cur];
        const f16* sBc = sB[cur];
        f16x8 af[4], bf[4];
        #pragma unroll
        for (int i = 0; i < 4; ++i) {
            af[i] = *(const f16x8*)(sAc + (wm * 64 + i * 16 + col16) * 32 + kq);
            bf[i] = *(const f16x8*)(sBc + (wn * 64 + i * 16 + col16) * 32 + kq);
        }
        #pragma unroll
        for (int mi = 0; mi < 4; ++mi)
            #pragma unroll
            for (int ni = 0; ni < 4; ++ni)
                acc[mi][ni] = __builtin_amdgcn_mfma_f32_16x16x32_f16(
                    af[mi], bf[ni], acc[mi][ni], 0, 0, 0);

        __builtin_amdgcn_s_barrier();            // readers done before overwrite
    }

    const int quad = lane >> 4;
    if (!head) {
        #pragma unroll
        for (int ni = 0; ni < 4; ++ni) {
            const int n = n0 + wn * 64 + ni * 16 + col16;
            const float b = bias[n];
            #pragma unroll
            for (int mi = 0; mi < 4; ++mi) {
                #pragma unroll
                for (int r = 0; r < 4; ++r) {
                    const int m = m0 + wm * 64 + mi * 16 + quad * 4 + r;
                    float v = fmaxf(acc[mi][ni][r] + b, 0.f);
                    C[(size_t)m * N + n] = (f16)v;
                }
            }
        }
    } else {
        float bb[4], w3c[4][3];
        #pragma unroll
        for (int ni = 0; ni < 4; ++ni) {
            const int n = n0 + wn * 64 + ni * 16 + col16;
            bb[ni] = bias[n];
            #pragma unroll
            for (int jj = 0; jj < 3; ++jj) w3c[ni][jj] = W3[n * 3 + jj];
        }
        const bool addb3 = (blockIdx.y == 0 && wn == 0);
        #pragma unroll
        for (int mi = 0; mi < 4; ++mi) {
            #pragma unroll
            for (int r = 0; r < 4; ++r) {
                float s0 = 0.f, s1 = 0.f, s2 = 0.f;
                #pragma unroll
                for (int ni = 0; ni < 4; ++ni) {
                    float v = fmaxf(acc[mi][ni][r] + bb[ni], 0.f);
                    s0 += v * w3c[ni][0];
                    s1 += v * w3c[ni][1];
                    s2 += v * w3c[ni][2];
                }
                #pragma unroll
                for (int mask = 1; mask <= 8; mask <<= 1) {
                    s0 += __shfl_xor(s0, mask);
                    s1 += __shfl_xor(s1, mask);
                    s2 += __shfl_xor(s2, mask);
                }
                if (col16 == 0) {
                    const int m = m0 + wm * 64 + mi * 16 + quad * 4 + r;
                    if (m < NLINES) {
                        atomicAdd(&out[m * 3 + 0], s0 + (addb3 ? b3[0] : 0.f));
                        atomicAdd(&out[m * 3 + 1], s1 + (addb3 ? b3[1] : 0.f));
                        atomicAdd(&out[m * 3 + 2], s2 + (addb3 ? b3[2] : 0.f));
                    }
                }
            }
        }
    }
}

// ---------------------------------------------------------------------------
extern "C" void kernel_launch(void* const* d_in, const int* in_sizes, int n_in,
                              void* d_out, int out_size, void* d_ws, size_t ws_size,
                              hipStream_t stream)
{
    const float* jloc = (const float*)d_in[0];
    const float* joff = (const float*)d_in[1];
    const float* loi  = (const float*)d_in[2];
    const int*   eidx = (const int*)d_in[3];
    const float* W1   = (const float*)d_in[4];
    const float* b1   = (const float*)d_in[5];
    const float* W2   = (const float*)d_in[6];
    const float* b2   = (const float*)d_in[7];
    const float* W3   = (const float*)d_in[8];
    const float* b3   = (const float*)d_in[9];
    float* out = (float*)d_out;

    char* ws = (char*)d_ws;
    f16*   loiT  = (f16*)(ws);                            // 4 MB
    f16*   W1T   = (f16*)(ws + ((size_t)4 << 20));        // 2 MB
    f16*   W2T   = (f16*)(ws + ((size_t)6 << 20));        // 2 MB
    float* juncs = (float*)(ws + ((size_t)8 << 20));      // 2.4 KB
    int*   count = (int*)(ws + ((size_t)8 << 20) + 4096);
    unsigned long long* cand =
        (unsigned long long*)(ws + ((size_t)8 << 20) + 8192);  // 32 KB
    f16*   feats = (f16*)(ws + ((size_t)9 << 20));        // 40 MB (MPAD x 1024)
    f16*   h1    = (f16*)(ws + ((size_t)51 << 20));       // 40 MB

    hipMemsetAsync(count, 0, sizeof(int), stream);
    preproc_kernel<<<dim3(764), dim3(256), 0, stream>>>(
        loi, loiT, W1, W1T, W2, W2T, jloc, cand, count, out, out_size);
    rank_junc_kernel<<<dim3(MAXCAND / 256), dim3(256), 0, stream>>>(
        cand, count, joff, juncs);
    sample_kernel<<<dim3(NLINES / 4), dim3(256), 0, stream>>>(loiT, juncs, eidx, feats);
    gemm_bias_relu_kernel<<<dim3(MPAD / 128, NDIM / 128), dim3(256), 0, stream>>>(
        feats, W1T, b1, h1, nullptr, nullptr, nullptr, KDIM, 0);
    gemm_bias_relu_kernel<<<dim3(MPAD / 128, NDIM / 128), dim3(256), 0, stream>>>(
        h1, W2T, b2, nullptr, W3, b3, out, KDIM, 1);
}

// Round 10
// 348.931 us; speedup vs baseline: 1.0222x; 1.0222x over previous
//
#include <hip/hip_runtime.h>
#include <cmath>

// ---------------------------------------------------------------------------
// WireframeDetector: NMS -> top-k 300 junctions -> line sampling (bilinear +
// maxpool) -> 3-layer MLP (fp16 MFMA for the two 1024x1024 GEMMs).
// R10: GEMM = R8's two-tile round (best measured; R9's partial-vmcnt dbuf was
//      slightly worse) + 4mx8n chunk swizzle: co-resident A working set
//      16MB < 32MB L2 (unlike natural order's 40MB) and ~3MB/XCD < 4MB
//      (unlike R5's XCD-pinned 4MB that thrashed).
// ---------------------------------------------------------------------------

typedef _Float16 f16;
typedef _Float16 f16x2 __attribute__((ext_vector_type(2)));
typedef _Float16 f16x8 __attribute__((ext_vector_type(8)));
typedef float f32x4 __attribute__((ext_vector_type(4)));

#define HWD 128
#define NPIX 16384            // 128*128
#define TOPK_N 300
#define NLINES 20000
#define MPAD 20096            // 157 * 128
#define MT157 157
#define KDIM 1024
#define NDIM 1024
#define MAXCAND 4096

// async global->LDS, 16B per lane; LDS dest = wave-uniform base + lane*16
#define G2L(gp, lp) __builtin_amdgcn_global_load_lds( \
    (const __attribute__((address_space(1))) void*)(gp), \
    (__attribute__((address_space(3))) void*)(lp), 16, 0, 0)

// ---------------------------------------------------------------------------
// Fused preprocessing, one dispatch of 764 blocks:
//   blocks 0..127   : transpose loi [C][H][W] fp32 -> loiT [H][W][C] fp16
//   blocks 128..639 : transpose W1/W2 [K][N] fp32 -> [N][K] fp16
//   blocks 640..703 : 3x3 NMS on jloc, survivors -> cand list (count pre-zeroed)
//   blocks 704..763 : zero out[60000] (consumed by gemm2's atomicAdd epilogue)
// ---------------------------------------------------------------------------
__global__ __launch_bounds__(256) void preproc_kernel(
    const float* __restrict__ loi, f16* __restrict__ loiT,
    const float* __restrict__ W1, f16* __restrict__ W1T,
    const float* __restrict__ W2, f16* __restrict__ W2T,
    const float* __restrict__ jloc, unsigned long long* __restrict__ cand,
    int* __restrict__ count, float* __restrict__ out, int out_n)
{
    const int bid = blockIdx.x;
    const int tid = threadIdx.x;
    if (bid < 128) {
        __shared__ f16 t[128 * 130];     // [x][c], +2 pad kills bank conflicts
        const int y = bid;
        #pragma unroll 4
        for (int it = 0; it < 64; ++it) {
            int idx = it * 256 + tid;    // c-major, x fast -> coalesced read
            int c = idx >> 7, x = idx & 127;
            t[x * 130 + c] = (f16)loi[c * NPIX + y * HWD + x];
        }
        __syncthreads();
        #pragma unroll
        for (int it = 0; it < 8; ++it) {
            int j = it * 256 + tid;      // 2048 chunks of 8 f16
            int x = j >> 4, cc = (j & 15) * 8;
            f16x8 v;
            #pragma unroll
            for (int u = 0; u < 8; ++u) v[u] = t[x * 130 + cc + u];
            *(f16x8*)(loiT + (y * HWD + x) * HWD + cc) = v;
        }
    } else if (bid < 640) {
        const int b = bid - 128;         // 0..511
        const float* W = (b < 256) ? W1 : W2;
        f16* Wt = (b < 256) ? W1T : W2T;
        const int bb = b & 255;
        __shared__ f16 t[64 * 66];
        const int k0 = (bb >> 4) * 64;
        const int n0 = (bb & 15) * 64;
        #pragma unroll 4
        for (int it = 0; it < 16; ++it) {
            int i = it * 256 + tid;      // coalesced read over n
            int r = i >> 6, c = i & 63;
            t[c * 66 + r] = (f16)W[(size_t)(k0 + r) * NDIM + n0 + c];
        }
        __syncthreads();
        #pragma unroll
        for (int it = 0; it < 2; ++it) {
            int j = it * 256 + tid;
            int nr = j >> 3, kc = (j & 7) * 8;
            f16x8 v;
            #pragma unroll
            for (int u = 0; u < 8; ++u) v[u] = t[nr * 66 + kc + u];
            *(f16x8*)(Wt + (size_t)(n0 + nr) * KDIM + k0 + kc) = v;
        }
    } else if (bid < 704) {
        const int p = (bid - 640) * 256 + tid;   // 64 blocks x 256 = 16384
        const int y = p >> 7, x = p & 127;
        const float c = jloc[p];
        float m = c;
        for (int dy = -1; dy <= 1; ++dy) {
            int yy = y + dy;
            if (yy < 0 || yy >= HWD) continue;
            for (int dx = -1; dx <= 1; ++dx) {
                int xx = x + dx;
                if (xx < 0 || xx >= HWD) continue;
                m = fmaxf(m, jloc[yy * HWD + xx]);
            }
        }
        if (c == m && c > 0.0f) {
            int pos = atomicAdd(count, 1);
            if (pos < MAXCAND) {
                unsigned int ub = __float_as_uint(c);
                cand[pos] = ((unsigned long long)ub << 32) |
                            (unsigned long long)(0xFFFFFFFFu - (unsigned int)p);
            }
        }
    } else {
        const int base = (bid - 704) * 1024 + tid * 4;   // 60 blocks cover 61440
        #pragma unroll
        for (int u = 0; u < 4; ++u)
            if (base + u < out_n) out[base + u] = 0.f;
    }
}

// ---------------------------------------------------------------------------
// Rank-select top-300, LDS-cached. Keys unique => ranks exact; matches
// jax.lax.top_k order (value desc, index asc).
// ---------------------------------------------------------------------------
__global__ __launch_bounds__(256) void rank_junc_kernel(
    const unsigned long long* __restrict__ cand, const int* __restrict__ count,
    const float* __restrict__ joff, float* __restrict__ juncs /* [300][2] */)
{
    __shared__ unsigned long long keys[MAXCAND];   // 32 KB
    const int n = min(*count, MAXCAND);
    const int t = blockIdx.x * 256 + threadIdx.x;  // 16 blocks = 4096 threads
    for (int i = threadIdx.x; i < n; i += 256)
        keys[i] = cand[i];
    __syncthreads();
    if (t >= n) return;
    const unsigned long long key = keys[t];
    int rank = 0;
    int j = 0;
    for (; j + 4 <= n; j += 4) {
        rank += (keys[j]     > key);
        rank += (keys[j + 1] > key);
        rank += (keys[j + 2] > key);
        rank += (keys[j + 3] > key);
    }
    for (; j < n; ++j) rank += (keys[j] > key);
    if (rank < TOPK_N) {
        unsigned int p = 0xFFFFFFFFu - (unsigned int)(key & 0xFFFFFFFFull);
        // x = idx%w + (sigmoid(joff0)-0.5) + 0.5 = idx%w + sigmoid(joff0)
        float sx = 1.0f / (1.0f + expf(-joff[p]));
        float sy = 1.0f / (1.0f + expf(-joff[NPIX + p]));
        juncs[2 * rank + 0] = (float)(p & 127) + sx;
        juncs[2 * rank + 1] = (float)(p >> 7) + sy;
    }
}

// ---------------------------------------------------------------------------
// Per-line sampling: 32 pts bilinear over loiT[H][W][C], maxpool groups of 4,
// write fp16 feats row. 4 lines/block; lane owns channels 2*lane, 2*lane+1.
// ---------------------------------------------------------------------------
__global__ __launch_bounds__(256) void sample_kernel(
    const f16* __restrict__ loiT, const float* __restrict__ juncs,
    const int* __restrict__ edge_idx, f16* __restrict__ feats)
{
    const int l = blockIdx.x * 4 + (threadIdx.x >> 6);
    const int lane = threadIdx.x & 63;
    const int e0 = edge_idx[2 * l], e1 = edge_idx[2 * l + 1];
    const float ux = juncs[2 * e0], uy = juncs[2 * e0 + 1];
    const float vx = juncs[2 * e1], vy = juncs[2 * e1 + 1];
    const int c2 = lane * 2;

    f16x8 o0, o1;
    #pragma unroll
    for (int p = 0; p < 8; ++p) {
        float m0 = -INFINITY, m1 = -INFINITY;
        #pragma unroll
        for (int jj = 0; jj < 4; ++jj) {
            const int j = p * 4 + jj;
            const float t = (float)j * (1.0f / 31.0f);
            const float px = ux * t + vx * (1.0f - t) - 0.5f;
            const float py = uy * t + vy * (1.0f - t) - 0.5f;
            float fx0 = fminf(fmaxf(floorf(px), 0.0f), 127.0f);
            float fy0 = fminf(fmaxf(floorf(py), 0.0f), 127.0f);
            float fx1 = fminf(fx0 + 1.0f, 127.0f);
            float fy1 = fminf(fy0 + 1.0f, 127.0f);
            int ix0 = (int)fx0, iy0 = (int)fy0, ix1 = (int)fx1, iy1 = (int)fy1;
            float w00 = (fy1 - py) * (fx1 - px);
            float w10 = (py - fy0) * (fx1 - px);
            float w01 = (fy1 - py) * (px - fx0);
            float w11 = (py - fy0) * (px - fx0);
            f16x2 v00 = *(const f16x2*)(loiT + (iy0 * HWD + ix0) * HWD + c2);
            f16x2 v10 = *(const f16x2*)(loiT + (iy1 * HWD + ix0) * HWD + c2);
            f16x2 v01 = *(const f16x2*)(loiT + (iy0 * HWD + ix1) * HWD + c2);
            f16x2 v11 = *(const f16x2*)(loiT + (iy1 * HWD + ix1) * HWD + c2);
            float s0 = (float)v00.x * w00 + (float)v10.x * w10 +
                       (float)v01.x * w01 + (float)v11.x * w11;
            float s1 = (float)v00.y * w00 + (float)v10.y * w10 +
                       (float)v01.y * w01 + (float)v11.y * w11;
            m0 = fmaxf(m0, s0);
            m1 = fmaxf(m1, s1);
        }
        o0[p] = (f16)m0;   // channel c2   -> feats[l, 16*lane + p]
        o1[p] = (f16)m1;   // channel c2+1 -> feats[l, 16*lane + 8 + p]
    }
    f16* dst = feats + (size_t)l * KDIM + lane * 16;
    *(f16x8*)(dst) = o0;
    *(f16x8*)(dst + 8) = o1;
}

// ---------------------------------------------------------------------------
// GEMM: 128x128 tile, 256 threads (2x2 waves of 64x64 subtiles). R8 loop:
// TWO BK=32 tiles per round in separate 8KB buffers (64B row stride), one
// vmcnt(0)+barrier drain per 32 MFMAs. Grid: 1D, 4mx8n chunks of 32 blocks —
// co-resident A working set ~16MB (fits 32MB L2), ~3MB/XCD (fits 4MB).
// head=0: C = relu(A@Bt^T + bias) stored fp16.
// head=1: v = relu(A@Bt^T + bias); out[m][j] += v . W3  (atomicAdd, + b3 once)
// ---------------------------------------------------------------------------
__global__ __launch_bounds__(256, 2) void gemm_bias_relu_kernel(
    const f16* __restrict__ A, const f16* __restrict__ Bt,
    const float* __restrict__ bias, f16* __restrict__ C,
    const float* __restrict__ W3, const float* __restrict__ b3,
    float* __restrict__ out, int K, int head)
{
    // chunk decode: 32 blocks per chunk = 4 m-tiles x 8 n-tiles
    const int cid = blockIdx.x >> 5;
    const int w = blockIdx.x & 31;
    const int mt = cid * 4 + (w >> 3);
    const int nt = w & 7;
    if (mt >= MT157) return;              // pad chunks (before any barrier)
    const int m0 = mt * 128;
    const int n0 = nt * 128;

    const int tid = threadIdx.x;
    const int wave = tid >> 6, lane = tid & 63;
    const int wm = wave >> 1, wn = wave & 1;
    const int N = NDIM;

    __shared__ f16 sA0[128 * 32];
    __shared__ f16 sA1[128 * 32];
    __shared__ f16 sB0[128 * 32];
    __shared__ f16 sB1[128 * 32];

    f32x4 acc[4][4];
    #pragma unroll
    for (int mi = 0; mi < 4; ++mi)
        #pragma unroll
        for (int ni = 0; ni < 4; ++ni)
            acc[mi][ni] = (f32x4){0.f, 0.f, 0.f, 0.f};

    // DMA staging (per 8KB buffer): 8 segs of 1KB (16 rows x 64B). Wave w
    // owns segs {w, w+4}. Lane i: row seg*16 + (i>>2), 16B chunk i&3 ->
    // monotonic per-lane addresses (DMA-coalescing-safe).
    const int rs0 = wave * 16 + (lane >> 2);
    const int rs1 = rs0 + 64;
    const int kc = (lane & 3) * 8;
    const f16* gA0 = A + (size_t)(m0 + rs0) * K + kc;
    const f16* gA1 = A + (size_t)(m0 + rs1) * K + kc;
    const f16* gB0 = Bt + (size_t)(n0 + rs0) * K + kc;
    const f16* gB1 = Bt + (size_t)(n0 + rs1) * K + kc;
    const int so0 = wave * 512;               // + lane*16B implicit
    const int so1 = (wave + 4) * 512;

    const int col16 = lane & 15;
    const int kq = (lane >> 4) * 8;

    for (int k0 = 0; k0 < K; k0 += 64) {
        __syncthreads();                      // prev round's LDS reads complete
        G2L(gA0 + k0, sA0 + so0);
        G2L(gA1 + k0, sA0 + so1);
        G2L(gB0 + k0, sB0 + so0);
        G2L(gB1 + k0, sB0 + so1);
        G2L(gA0 + k0 + 32, sA1 + so0);
        G2L(gA1 + k0 + 32, sA1 + so1);
        G2L(gB0 + k0 + 32, sB1 + so0);
        G2L(gB1 + k0 + 32, sB1 + so1);
        __builtin_amdgcn_s_waitcnt(0x0f70);   // vmcnt(0): own DMA done
        __syncthreads();                      // all waves' DMA done

        {
            f16x8 af[4], bf[4];
            #pragma unroll
            for (int i = 0; i < 4; ++i) {
                af[i] = *(const f16x8*)(sA0 + (wm * 64 + i * 16 + col16) * 32 + kq);
                bf[i] = *(const f16x8*)(sB0 + (wn * 64 + i * 16 + col16) * 32 + kq);
            }
            #pragma unroll
            for (int mi = 0; mi < 4; ++mi)
                #pragma unroll
                for (int ni = 0; ni < 4; ++ni)
                    acc[mi][ni] = __builtin_amdgcn_mfma_f32_16x16x32_f16(
                        af[mi], bf[ni], acc[mi][ni], 0, 0, 0);
        }
        {
            f16x8 af[4], bf[4];
            #pragma unroll
            for (int i = 0; i < 4; ++i) {
                af[i] = *(const f16x8*)(sA1 + (wm * 64 + i * 16 + col16) * 32 + kq);
                bf[i] = *(const f16x8*)(sB1 + (wn * 64 + i * 16 + col16) * 32 + kq);
            }
            #pragma unroll
            for (int mi = 0; mi < 4; ++mi)
                #pragma unroll
                for (int ni = 0; ni < 4; ++ni)
                    acc[mi][ni] = __builtin_amdgcn_mfma_f32_16x16x32_f16(
                        af[mi], bf[ni], acc[mi][ni], 0, 0, 0);
        }
    }

    const int quad = lane >> 4;
    if (!head) {
        #pragma unroll
        for (int ni = 0; ni < 4; ++ni) {
            const int n = n0 + wn * 64 + ni * 16 + col16;
            const float b = bias[n];
            #pragma unroll
            for (int mi = 0; mi < 4; ++mi) {
                #pragma unroll
                for (int r = 0; r < 4; ++r) {
                    const int m = m0 + wm * 64 + mi * 16 + quad * 4 + r;
                    float v = fmaxf(acc[mi][ni][r] + b, 0.f);
                    C[(size_t)m * N + n] = (f16)v;
                }
            }
        }
    } else {
        float bb[4], w3c[4][3];
        #pragma unroll
        for (int ni = 0; ni < 4; ++ni) {
            const int n = n0 + wn * 64 + ni * 16 + col16;
            bb[ni] = bias[n];
            #pragma unroll
            for (int jj = 0; jj < 3; ++jj) w3c[ni][jj] = W3[n * 3 + jj];
        }
        const bool addb3 = (nt == 0 && wn == 0);
        #pragma unroll
        for (int mi = 0; mi < 4; ++mi) {
            #pragma unroll
            for (int r = 0; r < 4; ++r) {
                float s0 = 0.f, s1 = 0.f, s2 = 0.f;
                #pragma unroll
                for (int ni = 0; ni < 4; ++ni) {
                    float v = fmaxf(acc[mi][ni][r] + bb[ni], 0.f);
                    s0 += v * w3c[ni][0];
                    s1 += v * w3c[ni][1];
                    s2 += v * w3c[ni][2];
                }
                #pragma unroll
                for (int mask = 1; mask <= 8; mask <<= 1) {
                    s0 += __shfl_xor(s0, mask);
                    s1 += __shfl_xor(s1, mask);
                    s2 += __shfl_xor(s2, mask);
                }
                if (col16 == 0) {
                    const int m = m0 + wm * 64 + mi * 16 + quad * 4 + r;
                    if (m < NLINES) {
                        atomicAdd(&out[m * 3 + 0], s0 + (addb3 ? b3[0] : 0.f));
                        atomicAdd(&out[m * 3 + 1], s1 + (addb3 ? b3[1] : 0.f));
                        atomicAdd(&out[m * 3 + 2], s2 + (addb3 ? b3[2] : 0.f));
                    }
                }
            }
        }
    }
}

// ---------------------------------------------------------------------------
extern "C" void kernel_launch(void* const* d_in, const int* in_sizes, int n_in,
                              void* d_out, int out_size, void* d_ws, size_t ws_size,
                              hipStream_t stream)
{
    const float* jloc = (const float*)d_in[0];
    const float* joff = (const float*)d_in[1];
    const float* loi  = (const float*)d_in[2];
    const int*   eidx = (const int*)d_in[3];
    const float* W1   = (const float*)d_in[4];
    const float* b1   = (const float*)d_in[5];
    const float* W2   = (const float*)d_in[6];
    const float* b2   = (const float*)d_in[7];
    const float* W3   = (const float*)d_in[8];
    const float* b3   = (const float*)d_in[9];
    float* out = (float*)d_out;

    char* ws = (char*)d_ws;
    f16*   loiT  = (f16*)(ws);                            // 4 MB
    f16*   W1T   = (f16*)(ws + ((size_t)4 << 20));        // 2 MB
    f16*   W2T   = (f16*)(ws + ((size_t)6 << 20));        // 2 MB
    float* juncs = (float*)(ws + ((size_t)8 << 20));      // 2.4 KB
    int*   count = (int*)(ws + ((size_t)8 << 20) + 4096);
    unsigned long long* cand =
        (unsigned long long*)(ws + ((size_t)8 << 20) + 8192);  // 32 KB
    f16*   feats = (f16*)(ws + ((size_t)9 << 20));        // 40 MB (MPAD x 1024)
    f16*   h1    = (f16*)(ws + ((size_t)51 << 20));       // 40 MB

    hipMemsetAsync(count, 0, sizeof(int), stream);
    preproc_kernel<<<dim3(764), dim3(256), 0, stream>>>(
        loi, loiT, W1, W1T, W2, W2T, jloc, cand, count, out, out_size);
    rank_junc_kernel<<<dim3(MAXCAND / 256), dim3(256), 0, stream>>>(
        cand, count, joff, juncs);
    sample_kernel<<<dim3(NLINES / 4), dim3(256), 0, stream>>>(loiT, juncs, eidx, feats);
    const int gblocks = 40 * 32;   // 40 chunks of (4m x 8n); 3 m-slots idle
    gemm_bias_relu_kernel<<<dim3(gblocks), dim3(256), 0, stream>>>(
        feats, W1T, b1, h1, nullptr, nullptr, nullptr, KDIM, 0);
    gemm_bias_relu_kernel<<<dim3(gblocks), dim3(256), 0, stream>>>(
        h1, W2T, b2, nullptr, W3, b3, out, KDIM, 1);
}

// Round 11
// 343.029 us; speedup vs baseline: 1.0398x; 1.0172x over previous
//
#include <hip/hip_runtime.h>
#include <cmath>

// ---------------------------------------------------------------------------
// WireframeDetector: NMS -> top-k 300 junctions -> line sampling (bilinear +
// maxpool) -> 3-layer MLP (fp16 MFMA for the two 1024x1024 GEMMs).
// R11: ordering levers retired (grid fully co-resident -> locality tricks
//      can't work; R5/R10 proved time uncorrelated with FETCH). Extend the
//      one lever that worked (drain amortization, R8): FOUR BK=32 tiles per
//      round in separate 8KB buffers (64B row stride -> no new conflicts),
//      one vmcnt(0)+barrier drain per 64 MFMAs (8 drains vs R8's 16).
//      Natural 2D grid.
// ---------------------------------------------------------------------------

typedef _Float16 f16;
typedef _Float16 f16x2 __attribute__((ext_vector_type(2)));
typedef _Float16 f16x8 __attribute__((ext_vector_type(8)));
typedef float f32x4 __attribute__((ext_vector_type(4)));

#define HWD 128
#define NPIX 16384            // 128*128
#define TOPK_N 300
#define NLINES 20000
#define MPAD 20096            // 157 * 128
#define KDIM 1024
#define NDIM 1024
#define MAXCAND 4096

// async global->LDS, 16B per lane; LDS dest = wave-uniform base + lane*16
#define G2L(gp, lp) __builtin_amdgcn_global_load_lds( \
    (const __attribute__((address_space(1))) void*)(gp), \
    (__attribute__((address_space(3))) void*)(lp), 16, 0, 0)

// ---------------------------------------------------------------------------
// Fused preprocessing, one dispatch of 764 blocks:
//   blocks 0..127   : transpose loi [C][H][W] fp32 -> loiT [H][W][C] fp16
//   blocks 128..639 : transpose W1/W2 [K][N] fp32 -> [N][K] fp16
//   blocks 640..703 : 3x3 NMS on jloc, survivors -> cand list (count pre-zeroed)
//   blocks 704..763 : zero out[60000] (consumed by gemm2's atomicAdd epilogue)
// ---------------------------------------------------------------------------
__global__ __launch_bounds__(256) void preproc_kernel(
    const float* __restrict__ loi, f16* __restrict__ loiT,
    const float* __restrict__ W1, f16* __restrict__ W1T,
    const float* __restrict__ W2, f16* __restrict__ W2T,
    const float* __restrict__ jloc, unsigned long long* __restrict__ cand,
    int* __restrict__ count, float* __restrict__ out, int out_n)
{
    const int bid = blockIdx.x;
    const int tid = threadIdx.x;
    if (bid < 128) {
        __shared__ f16 t[128 * 130];     // [x][c], +2 pad kills bank conflicts
        const int y = bid;
        #pragma unroll 4
        for (int it = 0; it < 64; ++it) {
            int idx = it * 256 + tid;    // c-major, x fast -> coalesced read
            int c = idx >> 7, x = idx & 127;
            t[x * 130 + c] = (f16)loi[c * NPIX + y * HWD + x];
        }
        __syncthreads();
        #pragma unroll
        for (int it = 0; it < 8; ++it) {
            int j = it * 256 + tid;      // 2048 chunks of 8 f16
            int x = j >> 4, cc = (j & 15) * 8;
            f16x8 v;
            #pragma unroll
            for (int u = 0; u < 8; ++u) v[u] = t[x * 130 + cc + u];
            *(f16x8*)(loiT + (y * HWD + x) * HWD + cc) = v;
        }
    } else if (bid < 640) {
        const int b = bid - 128;         // 0..511
        const float* W = (b < 256) ? W1 : W2;
        f16* Wt = (b < 256) ? W1T : W2T;
        const int bb = b & 255;
        __shared__ f16 t[64 * 66];
        const int k0 = (bb >> 4) * 64;
        const int n0 = (bb & 15) * 64;
        #pragma unroll 4
        for (int it = 0; it < 16; ++it) {
            int i = it * 256 + tid;      // coalesced read over n
            int r = i >> 6, c = i & 63;
            t[c * 66 + r] = (f16)W[(size_t)(k0 + r) * NDIM + n0 + c];
        }
        __syncthreads();
        #pragma unroll
        for (int it = 0; it < 2; ++it) {
            int j = it * 256 + tid;
            int nr = j >> 3, kc = (j & 7) * 8;
            f16x8 v;
            #pragma unroll
            for (int u = 0; u < 8; ++u) v[u] = t[nr * 66 + kc + u];
            *(f16x8*)(Wt + (size_t)(n0 + nr) * KDIM + k0 + kc) = v;
        }
    } else if (bid < 704) {
        const int p = (bid - 640) * 256 + tid;   // 64 blocks x 256 = 16384
        const int y = p >> 7, x = p & 127;
        const float c = jloc[p];
        float m = c;
        for (int dy = -1; dy <= 1; ++dy) {
            int yy = y + dy;
            if (yy < 0 || yy >= HWD) continue;
            for (int dx = -1; dx <= 1; ++dx) {
                int xx = x + dx;
                if (xx < 0 || xx >= HWD) continue;
                m = fmaxf(m, jloc[yy * HWD + xx]);
            }
        }
        if (c == m && c > 0.0f) {
            int pos = atomicAdd(count, 1);
            if (pos < MAXCAND) {
                unsigned int ub = __float_as_uint(c);
                cand[pos] = ((unsigned long long)ub << 32) |
                            (unsigned long long)(0xFFFFFFFFu - (unsigned int)p);
            }
        }
    } else {
        const int base = (bid - 704) * 1024 + tid * 4;   // 60 blocks cover 61440
        #pragma unroll
        for (int u = 0; u < 4; ++u)
            if (base + u < out_n) out[base + u] = 0.f;
    }
}

// ---------------------------------------------------------------------------
// Rank-select top-300, LDS-cached. Keys unique => ranks exact; matches
// jax.lax.top_k order (value desc, index asc).
// ---------------------------------------------------------------------------
__global__ __launch_bounds__(256) void rank_junc_kernel(
    const unsigned long long* __restrict__ cand, const int* __restrict__ count,
    const float* __restrict__ joff, float* __restrict__ juncs /* [300][2] */)
{
    __shared__ unsigned long long keys[MAXCAND];   // 32 KB
    const int n = min(*count, MAXCAND);
    const int t = blockIdx.x * 256 + threadIdx.x;  // 16 blocks = 4096 threads
    for (int i = threadIdx.x; i < n; i += 256)
        keys[i] = cand[i];
    __syncthreads();
    if (t >= n) return;
    const unsigned long long key = keys[t];
    int rank = 0;
    int j = 0;
    for (; j + 4 <= n; j += 4) {
        rank += (keys[j]     > key);
        rank += (keys[j + 1] > key);
        rank += (keys[j + 2] > key);
        rank += (keys[j + 3] > key);
    }
    for (; j < n; ++j) rank += (keys[j] > key);
    if (rank < TOPK_N) {
        unsigned int p = 0xFFFFFFFFu - (unsigned int)(key & 0xFFFFFFFFull);
        // x = idx%w + (sigmoid(joff0)-0.5) + 0.5 = idx%w + sigmoid(joff0)
        float sx = 1.0f / (1.0f + expf(-joff[p]));
        float sy = 1.0f / (1.0f + expf(-joff[NPIX + p]));
        juncs[2 * rank + 0] = (float)(p & 127) + sx;
        juncs[2 * rank + 1] = (float)(p >> 7) + sy;
    }
}

// ---------------------------------------------------------------------------
// Per-line sampling: 32 pts bilinear over loiT[H][W][C], maxpool groups of 4,
// write fp16 feats row. 4 lines/block; lane owns channels 2*lane, 2*lane+1.
// ---------------------------------------------------------------------------
__global__ __launch_bounds__(256) void sample_kernel(
    const f16* __restrict__ loiT, const float* __restrict__ juncs,
    const int* __restrict__ edge_idx, f16* __restrict__ feats)
{
    const int l = blockIdx.x * 4 + (threadIdx.x >> 6);
    const int lane = threadIdx.x & 63;
    const int e0 = edge_idx[2 * l], e1 = edge_idx[2 * l + 1];
    const float ux = juncs[2 * e0], uy = juncs[2 * e0 + 1];
    const float vx = juncs[2 * e1], vy = juncs[2 * e1 + 1];
    const int c2 = lane * 2;

    f16x8 o0, o1;
    #pragma unroll
    for (int p = 0; p < 8; ++p) {
        float m0 = -INFINITY, m1 = -INFINITY;
        #pragma unroll
        for (int jj = 0; jj < 4; ++jj) {
            const int j = p * 4 + jj;
            const float t = (float)j * (1.0f / 31.0f);
            const float px = ux * t + vx * (1.0f - t) - 0.5f;
            const float py = uy * t + vy * (1.0f - t) - 0.5f;
            float fx0 = fminf(fmaxf(floorf(px), 0.0f), 127.0f);
            float fy0 = fminf(fmaxf(floorf(py), 0.0f), 127.0f);
            float fx1 = fminf(fx0 + 1.0f, 127.0f);
            float fy1 = fminf(fy0 + 1.0f, 127.0f);
            int ix0 = (int)fx0, iy0 = (int)fy0, ix1 = (int)fx1, iy1 = (int)fy1;
            float w00 = (fy1 - py) * (fx1 - px);
            float w10 = (py - fy0) * (fx1 - px);
            float w01 = (fy1 - py) * (px - fx0);
            float w11 = (py - fy0) * (px - fx0);
            f16x2 v00 = *(const f16x2*)(loiT + (iy0 * HWD + ix0) * HWD + c2);
            f16x2 v10 = *(const f16x2*)(loiT + (iy1 * HWD + ix0) * HWD + c2);
            f16x2 v01 = *(const f16x2*)(loiT + (iy0 * HWD + ix1) * HWD + c2);
            f16x2 v11 = *(const f16x2*)(loiT + (iy1 * HWD + ix1) * HWD + c2);
            float s0 = (float)v00.x * w00 + (float)v10.x * w10 +
                       (float)v01.x * w01 + (float)v11.x * w11;
            float s1 = (float)v00.y * w00 + (float)v10.y * w10 +
                       (float)v01.y * w01 + (float)v11.y * w11;
            m0 = fmaxf(m0, s0);
            m1 = fmaxf(m1, s1);
        }
        o0[p] = (f16)m0;   // channel c2   -> feats[l, 16*lane + p]
        o1[p] = (f16)m1;   // channel c2+1 -> feats[l, 16*lane + 8 + p]
    }
    f16* dst = feats + (size_t)l * KDIM + lane * 16;
    *(f16x8*)(dst) = o0;
    *(f16x8*)(dst + 8) = o1;
}

// ---------------------------------------------------------------------------
// GEMM: 128x128 tile, 256 threads (2x2 waves of 64x64 subtiles). FOUR BK=32
// tiles per round in separate 8KB buffers (64B row stride each -> proven
// conflict profile), one vmcnt(0)+barrier drain per 64 MFMAs (8 drains for
// K=1024). LDS 64KB -> 2 blocks/CU. Natural 2D grid.
// head=0: C = relu(A@Bt^T + bias) stored fp16.
// head=1: v = relu(A@Bt^T + bias); out[m][j] += v . W3  (atomicAdd, + b3 once)
// ---------------------------------------------------------------------------
__global__ __launch_bounds__(256, 2) void gemm_bias_relu_kernel(
    const f16* __restrict__ A, const f16* __restrict__ Bt,
    const float* __restrict__ bias, f16* __restrict__ C,
    const float* __restrict__ W3, const float* __restrict__ b3,
    float* __restrict__ out, int K, int head)
{
    const int tid = threadIdx.x;
    const int wave = tid >> 6, lane = tid & 63;
    const int wm = wave >> 1, wn = wave & 1;
    const int m0 = blockIdx.x * 128;
    const int n0 = blockIdx.y * 128;
    const int N = NDIM;

    __shared__ f16 sA[4][128 * 32];   // 32 KB
    __shared__ f16 sB[4][128 * 32];   // 32 KB

    f32x4 acc[4][4];
    #pragma unroll
    for (int mi = 0; mi < 4; ++mi)
        #pragma unroll
        for (int ni = 0; ni < 4; ++ni)
            acc[mi][ni] = (f32x4){0.f, 0.f, 0.f, 0.f};

    // DMA staging (per 8KB buffer): 8 segs of 1KB (16 rows x 64B). Wave w
    // owns segs {w, w+4}. Lane i: row seg*16 + (i>>2), 16B chunk i&3 ->
    // monotonic per-lane addresses (DMA-coalescing-safe).
    const int rs0 = wave * 16 + (lane >> 2);
    const int rs1 = rs0 + 64;
    const int kc = (lane & 3) * 8;
    const f16* gA0 = A + (size_t)(m0 + rs0) * K + kc;
    const f16* gA1 = A + (size_t)(m0 + rs1) * K + kc;
    const f16* gB0 = Bt + (size_t)(n0 + rs0) * K + kc;
    const f16* gB1 = Bt + (size_t)(n0 + rs1) * K + kc;
    const int so0 = wave * 512;               // + lane*16B implicit
    const int so1 = (wave + 4) * 512;

    const int col16 = lane & 15;
    const int kq = (lane >> 4) * 8;

    for (int k0 = 0; k0 < K; k0 += 128) {
        __syncthreads();                      // prev round's LDS reads complete
        #pragma unroll
        for (int t = 0; t < 4; ++t) {
            G2L(gA0 + k0 + t * 32, sA[t] + so0);
            G2L(gA1 + k0 + t * 32, sA[t] + so1);
            G2L(gB0 + k0 + t * 32, sB[t] + so0);
            G2L(gB1 + k0 + t * 32, sB[t] + so1);
        }
        __builtin_amdgcn_s_waitcnt(0x0f70);   // vmcnt(0): own DMA done
        __syncthreads();                      // all waves' DMA done

        #pragma unroll
        for (int t = 0; t < 4; ++t) {
            f16x8 af[4], bf[4];
            #pragma unroll
            for (int i = 0; i < 4; ++i) {
                af[i] = *(const f16x8*)(sA[t] + (wm * 64 + i * 16 + col16) * 32 + kq);
                bf[i] = *(const f16x8*)(sB[t] + (wn * 64 + i * 16 + col16) * 32 + kq);
            }
            #pragma unroll
            for (int mi = 0; mi < 4; ++mi)
                #pragma unroll
                for (int ni = 0; ni < 4; ++ni)
                    acc[mi][ni] = __builtin_amdgcn_mfma_f32_16x16x32_f16(
                        af[mi], bf[ni], acc[mi][ni], 0, 0, 0);
        }
    }

    const int quad = lane >> 4;
    if (!head) {
        #pragma unroll
        for (int ni = 0; ni < 4; ++ni) {
            const int n = n0 + wn * 64 + ni * 16 + col16;
            const float b = bias[n];
            #pragma unroll
            for (int mi = 0; mi < 4; ++mi) {
                #pragma unroll
                for (int r = 0; r < 4; ++r) {
                    const int m = m0 + wm * 64 + mi * 16 + quad * 4 + r;
                    float v = fmaxf(acc[mi][ni][r] + b, 0.f);
                    C[(size_t)m * N + n] = (f16)v;
                }
            }
        }
    } else {
        float bb[4], w3c[4][3];
        #pragma unroll
        for (int ni = 0; ni < 4; ++ni) {
            const int n = n0 + wn * 64 + ni * 16 + col16;
            bb[ni] = bias[n];
            #pragma unroll
            for (int jj = 0; jj < 3; ++jj) w3c[ni][jj] = W3[n * 3 + jj];
        }
        const bool addb3 = (blockIdx.y == 0 && wn == 0);
        #pragma unroll
        for (int mi = 0; mi < 4; ++mi) {
            #pragma unroll
            for (int r = 0; r < 4; ++r) {
                float s0 = 0.f, s1 = 0.f, s2 = 0.f;
                #pragma unroll
                for (int ni = 0; ni < 4; ++ni) {
                    float v = fmaxf(acc[mi][ni][r] + bb[ni], 0.f);
                    s0 += v * w3c[ni][0];
                    s1 += v * w3c[ni][1];
                    s2 += v * w3c[ni][2];
                }
                #pragma unroll
                for (int mask = 1; mask <= 8; mask <<= 1) {
                    s0 += __shfl_xor(s0, mask);
                    s1 += __shfl_xor(s1, mask);
                    s2 += __shfl_xor(s2, mask);
                }
                if (col16 == 0) {
                    const int m = m0 + wm * 64 + mi * 16 + quad * 4 + r;
                    if (m < NLINES) {
                        atomicAdd(&out[m * 3 + 0], s0 + (addb3 ? b3[0] : 0.f));
                        atomicAdd(&out[m * 3 + 1], s1 + (addb3 ? b3[1] : 0.f));
                        atomicAdd(&out[m * 3 + 2], s2 + (addb3 ? b3[2] : 0.f));
                    }
                }
            }
        }
    }
}

// ---------------------------------------------------------------------------
extern "C" void kernel_launch(void* const* d_in, const int* in_sizes, int n_in,
                              void* d_out, int out_size, void* d_ws, size_t ws_size,
                              hipStream_t stream)
{
    const float* jloc = (const float*)d_in[0];
    const float* joff = (const float*)d_in[1];
    const float* loi  = (const float*)d_in[2];
    const int*   eidx = (const int*)d_in[3];
    const float* W1   = (const float*)d_in[4];
    const float* b1   = (const float*)d_in[5];
    const float* W2   = (const float*)d_in[6];
    const float* b2   = (const float*)d_in[7];
    const float* W3   = (const float*)d_in[8];
    const float* b3   = (const float*)d_in[9];
    float* out = (float*)d_out;

    char* ws = (char*)d_ws;
    f16*   loiT  = (f16*)(ws);                            // 4 MB
    f16*   W1T   = (f16*)(ws + ((size_t)4 << 20));        // 2 MB
    f16*   W2T   = (f16*)(ws + ((size_t)6 << 20));        // 2 MB
    float* juncs = (float*)(ws + ((size_t)8 << 20));      // 2.4 KB
    int*   count = (int*)(ws + ((size_t)8 << 20) + 4096);
    unsigned long long* cand =
        (unsigned long long*)(ws + ((size_t)8 << 20) + 8192);  // 32 KB
    f16*   feats = (f16*)(ws + ((size_t)9 << 20));        // 40 MB (MPAD x 1024)
    f16*   h1    = (f16*)(ws + ((size_t)51 << 20));       // 40 MB

    hipMemsetAsync(count, 0, sizeof(int), stream);
    preproc_kernel<<<dim3(764), dim3(256), 0, stream>>>(
        loi, loiT, W1, W1T, W2, W2T, jloc, cand, count, out, out_size);
    rank_junc_kernel<<<dim3(MAXCAND / 256), dim3(256), 0, stream>>>(
        cand, count, joff, juncs);
    sample_kernel<<<dim3(NLINES / 4), dim3(256), 0, stream>>>(loiT, juncs, eidx, feats);
    gemm_bias_relu_kernel<<<dim3(MPAD / 128, NDIM / 128), dim3(256), 0, stream>>>(
        feats, W1T, b1, h1, nullptr, nullptr, nullptr, KDIM, 0);
    gemm_bias_relu_kernel<<<dim3(MPAD / 128, NDIM / 128), dim3(256), 0, stream>>>(
        h1, W2T, b2, nullptr, W3, b3, out, KDIM, 1);
}

// Round 12
// 334.364 us; speedup vs baseline: 1.0667x; 1.0259x over previous
//
#include <hip/hip_runtime.h>
#include <cmath>

// ---------------------------------------------------------------------------
// WireframeDetector: NMS -> top-k 300 junctions -> line sampling (bilinear +
// maxpool) -> 3-layer MLP (fp16 MFMA for the two 1024x1024 GEMMs).
// R12: K-chunk-tiled operand layout. R2..R11 showed GEMM time pinned at
//      staged-bytes / ~6 TB/s (10 B/cyc/CU = HBM-copy-class rate) regardless
//      of drains/ordering/occupancy — the VMEM->LDS path is the wall, and
//      every G2L read 16 lines at stride 2048B. New layout: (m,k) at
//      ((k>>5)*M + m)*32 + (k&31) => each staged 8KB tile is CONTIGUOUS;
//      G2L bursts are 1KB sequential. LDS layout/fragments/MFMA unchanged.
// ---------------------------------------------------------------------------

typedef _Float16 f16;
typedef _Float16 f16x2 __attribute__((ext_vector_type(2)));
typedef _Float16 f16x8 __attribute__((ext_vector_type(8)));
typedef float f32x4 __attribute__((ext_vector_type(4)));

#define HWD 128
#define NPIX 16384            // 128*128
#define TOPK_N 300
#define NLINES 20000
#define MPAD 20096            // 157 * 128
#define KDIM 1024
#define NDIM 1024
#define MAXCAND 4096

// async global->LDS, 16B per lane; LDS dest = wave-uniform base + lane*16
#define G2L(gp, lp) __builtin_amdgcn_global_load_lds( \
    (const __attribute__((address_space(1))) void*)(gp), \
    (__attribute__((address_space(3))) void*)(lp), 16, 0, 0)

// ---------------------------------------------------------------------------
// Fused preprocessing, one dispatch of 764 blocks:
//   blocks 0..127   : transpose loi [C][H][W] fp32 -> loiT [H][W][C] fp16
//   blocks 128..639 : W1/W2 [K][N] fp32 -> K-chunk-tiled fp16
//                     Wt[((k>>5)*1024 + n)*32 + (k&31)]
//   blocks 640..703 : 3x3 NMS on jloc, survivors -> cand list (count pre-zeroed)
//   blocks 704..763 : zero out[60000] (consumed by gemm2's atomicAdd epilogue)
// ---------------------------------------------------------------------------
__global__ __launch_bounds__(256) void preproc_kernel(
    const float* __restrict__ loi, f16* __restrict__ loiT,
    const float* __restrict__ W1, f16* __restrict__ W1T,
    const float* __restrict__ W2, f16* __restrict__ W2T,
    const float* __restrict__ jloc, unsigned long long* __restrict__ cand,
    int* __restrict__ count, float* __restrict__ out, int out_n)
{
    const int bid = blockIdx.x;
    const int tid = threadIdx.x;
    if (bid < 128) {
        __shared__ f16 t[128 * 130];     // [x][c], +2 pad kills bank conflicts
        const int y = bid;
        #pragma unroll 4
        for (int it = 0; it < 64; ++it) {
            int idx = it * 256 + tid;    // c-major, x fast -> coalesced read
            int c = idx >> 7, x = idx & 127;
            t[x * 130 + c] = (f16)loi[c * NPIX + y * HWD + x];
        }
        __syncthreads();
        #pragma unroll
        for (int it = 0; it < 8; ++it) {
            int j = it * 256 + tid;      // 2048 chunks of 8 f16
            int x = j >> 4, cc = (j & 15) * 8;
            f16x8 v;
            #pragma unroll
            for (int u = 0; u < 8; ++u) v[u] = t[x * 130 + cc + u];
            *(f16x8*)(loiT + (y * HWD + x) * HWD + cc) = v;
        }
    } else if (bid < 640) {
        const int b = bid - 128;         // 0..511
        const float* W = (b < 256) ? W1 : W2;
        f16* Wt = (b < 256) ? W1T : W2T;
        const int bb = b & 255;
        __shared__ f16 t[64 * 66];
        const int k0 = (bb >> 4) * 64;
        const int n0 = (bb & 15) * 64;
        #pragma unroll 4
        for (int it = 0; it < 16; ++it) {
            int i = it * 256 + tid;      // coalesced read over n
            int r = i >> 6, c = i & 63;
            t[c * 66 + r] = (f16)W[(size_t)(k0 + r) * NDIM + n0 + c];
        }
        __syncthreads();
        #pragma unroll
        for (int it = 0; it < 2; ++it) {
            int j = it * 256 + tid;
            int nr = j >> 3, kc = (j & 7) * 8;
            f16x8 v;
            #pragma unroll
            for (int u = 0; u < 8; ++u) v[u] = t[nr * 66 + kc + u];
            const int kk = k0 + kc;      // multiple of 8
            *(f16x8*)(Wt + ((size_t)(kk >> 5) * NDIM + (n0 + nr)) * 32 + (kk & 31)) = v;
        }
    } else if (bid < 704) {
        const int p = (bid - 640) * 256 + tid;   // 64 blocks x 256 = 16384
        const int y = p >> 7, x = p & 127;
        const float c = jloc[p];
        float m = c;
        for (int dy = -1; dy <= 1; ++dy) {
            int yy = y + dy;
            if (yy < 0 || yy >= HWD) continue;
            for (int dx = -1; dx <= 1; ++dx) {
                int xx = x + dx;
                if (xx < 0 || xx >= HWD) continue;
                m = fmaxf(m, jloc[yy * HWD + xx]);
            }
        }
        if (c == m && c > 0.0f) {
            int pos = atomicAdd(count, 1);
            if (pos < MAXCAND) {
                unsigned int ub = __float_as_uint(c);
                cand[pos] = ((unsigned long long)ub << 32) |
                            (unsigned long long)(0xFFFFFFFFu - (unsigned int)p);
            }
        }
    } else {
        const int base = (bid - 704) * 1024 + tid * 4;   // 60 blocks cover 61440
        #pragma unroll
        for (int u = 0; u < 4; ++u)
            if (base + u < out_n) out[base + u] = 0.f;
    }
}

// ---------------------------------------------------------------------------
// Rank-select top-300, LDS-cached. Keys unique => ranks exact; matches
// jax.lax.top_k order (value desc, index asc).
// ---------------------------------------------------------------------------
__global__ __launch_bounds__(256) void rank_junc_kernel(
    const unsigned long long* __restrict__ cand, const int* __restrict__ count,
    const float* __restrict__ joff, float* __restrict__ juncs /* [300][2] */)
{
    __shared__ unsigned long long keys[MAXCAND];   // 32 KB
    const int n = min(*count, MAXCAND);
    const int t = blockIdx.x * 256 + threadIdx.x;  // 16 blocks = 4096 threads
    for (int i = threadIdx.x; i < n; i += 256)
        keys[i] = cand[i];
    __syncthreads();
    if (t >= n) return;
    const unsigned long long key = keys[t];
    int rank = 0;
    int j = 0;
    for (; j + 4 <= n; j += 4) {
        rank += (keys[j]     > key);
        rank += (keys[j + 1] > key);
        rank += (keys[j + 2] > key);
        rank += (keys[j + 3] > key);
    }
    for (; j < n; ++j) rank += (keys[j] > key);
    if (rank < TOPK_N) {
        unsigned int p = 0xFFFFFFFFu - (unsigned int)(key & 0xFFFFFFFFull);
        // x = idx%w + (sigmoid(joff0)-0.5) + 0.5 = idx%w + sigmoid(joff0)
        float sx = 1.0f / (1.0f + expf(-joff[p]));
        float sy = 1.0f / (1.0f + expf(-joff[NPIX + p]));
        juncs[2 * rank + 0] = (float)(p & 127) + sx;
        juncs[2 * rank + 1] = (float)(p >> 7) + sy;
    }
}

// ---------------------------------------------------------------------------
// Per-line sampling: 32 pts bilinear over loiT[H][W][C], maxpool groups of 4,
// write fp16 feats row in K-chunk-tiled layout. 4 lines/block; lane owns
// channels 2*lane, 2*lane+1 (feature k = 16*lane..16*lane+15).
// ---------------------------------------------------------------------------
__global__ __launch_bounds__(256) void sample_kernel(
    const f16* __restrict__ loiT, const float* __restrict__ juncs,
    const int* __restrict__ edge_idx, f16* __restrict__ feats)
{
    const int l = blockIdx.x * 4 + (threadIdx.x >> 6);
    const int lane = threadIdx.x & 63;
    const int e0 = edge_idx[2 * l], e1 = edge_idx[2 * l + 1];
    const float ux = juncs[2 * e0], uy = juncs[2 * e0 + 1];
    const float vx = juncs[2 * e1], vy = juncs[2 * e1 + 1];
    const int c2 = lane * 2;

    f16x8 o0, o1;
    #pragma unroll
    for (int p = 0; p < 8; ++p) {
        float m0 = -INFINITY, m1 = -INFINITY;
        #pragma unroll
        for (int jj = 0; jj < 4; ++jj) {
            const int j = p * 4 + jj;
            const float t = (float)j * (1.0f / 31.0f);
            const float px = ux * t + vx * (1.0f - t) - 0.5f;
            const float py = uy * t + vy * (1.0f - t) - 0.5f;
            float fx0 = fminf(fmaxf(floorf(px), 0.0f), 127.0f);
            float fy0 = fminf(fmaxf(floorf(py), 0.0f), 127.0f);
            float fx1 = fminf(fx0 + 1.0f, 127.0f);
            float fy1 = fminf(fy0 + 1.0f, 127.0f);
            int ix0 = (int)fx0, iy0 = (int)fy0, ix1 = (int)fx1, iy1 = (int)fy1;
            float w00 = (fy1 - py) * (fx1 - px);
            float w10 = (py - fy0) * (fx1 - px);
            float w01 = (fy1 - py) * (px - fx0);
            float w11 = (py - fy0) * (px - fx0);
            f16x2 v00 = *(const f16x2*)(loiT + (iy0 * HWD + ix0) * HWD + c2);
            f16x2 v10 = *(const f16x2*)(loiT + (iy1 * HWD + ix0) * HWD + c2);
            f16x2 v01 = *(const f16x2*)(loiT + (iy0 * HWD + ix1) * HWD + c2);
            f16x2 v11 = *(const f16x2*)(loiT + (iy1 * HWD + ix1) * HWD + c2);
            float s0 = (float)v00.x * w00 + (float)v10.x * w10 +
                       (float)v01.x * w01 + (float)v11.x * w11;
            float s1 = (float)v00.y * w00 + (float)v10.y * w10 +
                       (float)v01.y * w01 + (float)v11.y * w11;
            m0 = fmaxf(m0, s0);
            m1 = fmaxf(m1, s1);
        }
        o0[p] = (f16)m0;   // feature k = 16*lane + p
        o1[p] = (f16)m1;   // feature k = 16*lane + 8 + p
    }
    // tiled: (l, k) -> ((k>>5)*MPAD + l)*32 + (k&31); k-chunk = lane>>1,
    // within-chunk = (lane&1)*16.
    f16* dst = feats + ((size_t)(lane >> 1) * MPAD + l) * 32 + (lane & 1) * 16;
    *(f16x8*)(dst) = o0;
    *(f16x8*)(dst + 8) = o1;
}

// ---------------------------------------------------------------------------
// GEMM: 128x128 tile, 256 threads (2x2 waves of 64x64 subtiles). R8's
// two-tile round (one vmcnt(0)+barrier drain per 32 MFMAs), but operands in
// K-chunk-tiled layout: each 8KB staged tile is CONTIGUOUS in memory, so
// every G2L is a 1KB sequential burst (was 16 lines at stride 2KB).
// LDS layout identical to before ([row][32] f16) -> fragments unchanged.
// head=0: C = relu(A@Bt^T + bias), stored K-chunk-tiled fp16.
// head=1: v = relu(A@Bt^T + bias); out[m][j] += v . W3  (atomicAdd, + b3 once)
// ---------------------------------------------------------------------------
__global__ __launch_bounds__(256, 2) void gemm_bias_relu_kernel(
    const f16* __restrict__ A, const f16* __restrict__ Bt,
    const float* __restrict__ bias, f16* __restrict__ C,
    const float* __restrict__ W3, const float* __restrict__ b3,
    float* __restrict__ out, int K, int head)
{
    const int tid = threadIdx.x;
    const int wave = tid >> 6, lane = tid & 63;
    const int wm = wave >> 1, wn = wave & 1;
    const int m0 = blockIdx.x * 128;
    const int n0 = blockIdx.y * 128;
    const int N = NDIM;

    __shared__ f16 sA0[128 * 32];
    __shared__ f16 sA1[128 * 32];
    __shared__ f16 sB0[128 * 32];
    __shared__ f16 sB1[128 * 32];

    f32x4 acc[4][4];
    #pragma unroll
    for (int mi = 0; mi < 4; ++mi)
        #pragma unroll
        for (int ni = 0; ni < 4; ++ni)
            acc[mi][ni] = (f32x4){0.f, 0.f, 0.f, 0.f};

    // Tiled staging: chunk c of A-tile = contiguous 4096 f16 at
    // A + (c*MPAD + m0)*32. Wave w stages segs {w, w+4} (1KB each);
    // lane i deposits/fetches seg_base + i*16B. Global == LDS order.
    const size_t strideA = (size_t)MPAD * 32;   // f16 per k-chunk
    const size_t strideB = (size_t)NDIM * 32;
    const f16* gA = A + (size_t)m0 * 32 + wave * 512 + lane * 8;
    const f16* gB = Bt + (size_t)n0 * 32 + wave * 512 + lane * 8;
    const int so0 = wave * 512;                 // + lane*16B implicit
    const int so1 = (wave + 4) * 512;

    const int col16 = lane & 15;
    const int kq = (lane >> 4) * 8;

    const int NC = K >> 5;                      // 32 k-chunks
    for (int c0 = 0; c0 < NC; c0 += 2) {
        const f16* a0 = gA + (size_t)c0 * strideA;
        const f16* a1 = a0 + strideA;
        const f16* b0 = gB + (size_t)c0 * strideB;
        const f16* b1 = b0 + strideB;
        __syncthreads();                      // prev round's LDS reads complete
        G2L(a0, sA0 + so0);
        G2L(a0 + 2048, sA0 + so1);
        G2L(b0, sB0 + so0);
        G2L(b0 + 2048, sB0 + so1);
        G2L(a1, sA1 + so0);
        G2L(a1 + 2048, sA1 + so1);
        G2L(b1, sB1 + so0);
        G2L(b1 + 2048, sB1 + so1);
        __builtin_amdgcn_s_waitcnt(0x0f70);   // vmcnt(0): own DMA done
        __syncthreads();                      // all waves' DMA done

        {
            f16x8 af[4], bf[4];
            #pragma unroll
            for (int i = 0; i < 4; ++i) {
                af[i] = *(const f16x8*)(sA0 + (wm * 64 + i * 16 + col16) * 32 + kq);
                bf[i] = *(const f16x8*)(sB0 + (wn * 64 + i * 16 + col16) * 32 + kq);
            }
            #pragma unroll
            for (int mi = 0; mi < 4; ++mi)
                #pragma unroll
                for (int ni = 0; ni < 4; ++ni)
                    acc[mi][ni] = __builtin_amdgcn_mfma_f32_16x16x32_f16(
                        af[mi], bf[ni], acc[mi][ni], 0, 0, 0);
        }
        {
            f16x8 af[4], bf[4];
            #pragma unroll
            for (int i = 0; i < 4; ++i) {
                af[i] = *(const f16x8*)(sA1 + (wm * 64 + i * 16 + col16) * 32 + kq);
                bf[i] = *(const f16x8*)(sB1 + (wn * 64 + i * 16 + col16) * 32 + kq);
            }
            #pragma unroll
            for (int mi = 0; mi < 4; ++mi)
                #pragma unroll
                for (int ni = 0; ni < 4; ++ni)
                    acc[mi][ni] = __builtin_amdgcn_mfma_f32_16x16x32_f16(
                        af[mi], bf[ni], acc[mi][ni], 0, 0, 0);
        }
    }

    const int quad = lane >> 4;
    if (!head) {
        #pragma unroll
        for (int ni = 0; ni < 4; ++ni) {
            const int n = n0 + wn * 64 + ni * 16 + col16;
            const float b = bias[n];
            const size_t cb = ((size_t)(n >> 5) * MPAD) * 32 + (n & 31);
            #pragma unroll
            for (int mi = 0; mi < 4; ++mi) {
                #pragma unroll
                for (int r = 0; r < 4; ++r) {
                    const int m = m0 + wm * 64 + mi * 16 + quad * 4 + r;
                    float v = fmaxf(acc[mi][ni][r] + b, 0.f);
                    C[cb + (size_t)m * 32] = (f16)v;   // K-chunk-tiled
                }
            }
        }
    } else {
        float bb[4], w3c[4][3];
        #pragma unroll
        for (int ni = 0; ni < 4; ++ni) {
            const int n = n0 + wn * 64 + ni * 16 + col16;
            bb[ni] = bias[n];
            #pragma unroll
            for (int jj = 0; jj < 3; ++jj) w3c[ni][jj] = W3[n * 3 + jj];
        }
        const bool addb3 = (blockIdx.y == 0 && wn == 0);
        #pragma unroll
        for (int mi = 0; mi < 4; ++mi) {
            #pragma unroll
            for (int r = 0; r < 4; ++r) {
                float s0 = 0.f, s1 = 0.f, s2 = 0.f;
                #pragma unroll
                for (int ni = 0; ni < 4; ++ni) {
                    float v = fmaxf(acc[mi][ni][r] + bb[ni], 0.f);
                    s0 += v * w3c[ni][0];
                    s1 += v * w3c[ni][1];
                    s2 += v * w3c[ni][2];
                }
                #pragma unroll
                for (int mask = 1; mask <= 8; mask <<= 1) {
                    s0 += __shfl_xor(s0, mask);
                    s1 += __shfl_xor(s1, mask);
                    s2 += __shfl_xor(s2, mask);
                }
                if (col16 == 0) {
                    const int m = m0 + wm * 64 + mi * 16 + quad * 4 + r;
                    if (m < NLINES) {
                        atomicAdd(&out[m * 3 + 0], s0 + (addb3 ? b3[0] : 0.f));
                        atomicAdd(&out[m * 3 + 1], s1 + (addb3 ? b3[1] : 0.f));
                        atomicAdd(&out[m * 3 + 2], s2 + (addb3 ? b3[2] : 0.f));
                    }
                }
            }
        }
    }
}

// ---------------------------------------------------------------------------
extern "C" void kernel_launch(void* const* d_in, const int* in_sizes, int n_in,
                              void* d_out, int out_size, void* d_ws, size_t ws_size,
                              hipStream_t stream)
{
    const float* jloc = (const float*)d_in[0];
    const float* joff = (const float*)d_in[1];
    const float* loi  = (const float*)d_in[2];
    const int*   eidx = (const int*)d_in[3];
    const float* W1   = (const float*)d_in[4];
    const float* b1   = (const float*)d_in[5];
    const float* W2   = (const float*)d_in[6];
    const float* b2   = (const float*)d_in[7];
    const float* W3   = (const float*)d_in[8];
    const float* b3   = (const float*)d_in[9];
    float* out = (float*)d_out;

    char* ws = (char*)d_ws;
    f16*   loiT  = (f16*)(ws);                            // 4 MB
    f16*   W1T   = (f16*)(ws + ((size_t)4 << 20));        // 2 MB
    f16*   W2T   = (f16*)(ws + ((size_t)6 << 20));        // 2 MB
    float* juncs = (float*)(ws + ((size_t)8 << 20));      // 2.4 KB
    int*   count = (int*)(ws + ((size_t)8 << 20) + 4096);
    unsigned long long* cand =
        (unsigned long long*)(ws + ((size_t)8 << 20) + 8192);  // 32 KB
    f16*   feats = (f16*)(ws + ((size_t)9 << 20));        // 40 MB (tiled MPADx1024)
    f16*   h1    = (f16*)(ws + ((size_t)51 << 20));       // 40 MB (tiled)

    hipMemsetAsync(count, 0, sizeof(int), stream);
    preproc_kernel<<<dim3(764), dim3(256), 0, stream>>>(
        loi, loiT, W1, W1T, W2, W2T, jloc, cand, count, out, out_size);
    rank_junc_kernel<<<dim3(MAXCAND / 256), dim3(256), 0, stream>>>(
        cand, count, joff, juncs);
    sample_kernel<<<dim3(NLINES / 4), dim3(256), 0, stream>>>(loiT, juncs, eidx, feats);
    gemm_bias_relu_kernel<<<dim3(MPAD / 128, NDIM / 128), dim3(256), 0, stream>>>(
        feats, W1T, b1, h1, nullptr, nullptr, nullptr, KDIM, 0);
    gemm_bias_relu_kernel<<<dim3(MPAD / 128, NDIM / 128), dim3(256), 0, stream>>>(
        h1, W2T, b2, nullptr, W3, b3, out, KDIM, 1);
}

// Round 13
// 310.881 us; speedup vs baseline: 1.1473x; 1.0755x over previous
//
#include <hip/hip_runtime.h>
#include <cmath>

// ---------------------------------------------------------------------------
// WireframeDetector: NMS -> top-k 300 junctions -> line sampling (bilinear +
// maxpool) -> 3-layer MLP (fp16 MFMA for the two 1024x1024 GEMMs).
// R13: sample_kernel rewrite — per-point bilinear address/weight math was
//      computed redundantly by all 64 lanes (~80 us of duplicate VALU, the
//      hidden sink behind the 140 us non-GEMM budget). Now lanes 0-31
//      precompute per-point taps into LDS; the channel loop reads them as
//      wave-uniform broadcasts. GEMM kept at R12 (structural floor ~97 us).
// ---------------------------------------------------------------------------

typedef _Float16 f16;
typedef _Float16 f16x2 __attribute__((ext_vector_type(2)));
typedef _Float16 f16x8 __attribute__((ext_vector_type(8)));
typedef float f32x4 __attribute__((ext_vector_type(4)));

#define HWD 128
#define NPIX 16384            // 128*128
#define TOPK_N 300
#define NLINES 20000
#define MPAD 20096            // 157 * 128
#define KDIM 1024
#define NDIM 1024
#define MAXCAND 4096

// async global->LDS, 16B per lane; LDS dest = wave-uniform base + lane*16
#define G2L(gp, lp) __builtin_amdgcn_global_load_lds( \
    (const __attribute__((address_space(1))) void*)(gp), \
    (__attribute__((address_space(3))) void*)(lp), 16, 0, 0)

// ---------------------------------------------------------------------------
// Fused preprocessing, one dispatch of 764 blocks:
//   blocks 0..127   : transpose loi [C][H][W] fp32 -> loiT [H][W][C] fp16
//   blocks 128..639 : W1/W2 [K][N] fp32 -> K-chunk-tiled fp16
//                     Wt[((k>>5)*1024 + n)*32 + (k&31)]
//   blocks 640..703 : 3x3 NMS on jloc, survivors -> cand list (count pre-zeroed)
//   blocks 704..763 : zero out[60000] (consumed by gemm2's atomicAdd epilogue)
// ---------------------------------------------------------------------------
__global__ __launch_bounds__(256) void preproc_kernel(
    const float* __restrict__ loi, f16* __restrict__ loiT,
    const float* __restrict__ W1, f16* __restrict__ W1T,
    const float* __restrict__ W2, f16* __restrict__ W2T,
    const float* __restrict__ jloc, unsigned long long* __restrict__ cand,
    int* __restrict__ count, float* __restrict__ out, int out_n)
{
    const int bid = blockIdx.x;
    const int tid = threadIdx.x;
    if (bid < 128) {
        __shared__ f16 t[128 * 130];     // [x][c], +2 pad kills bank conflicts
        const int y = bid;
        #pragma unroll 4
        for (int it = 0; it < 64; ++it) {
            int idx = it * 256 + tid;    // c-major, x fast -> coalesced read
            int c = idx >> 7, x = idx & 127;
            t[x * 130 + c] = (f16)loi[c * NPIX + y * HWD + x];
        }
        __syncthreads();
        #pragma unroll
        for (int it = 0; it < 8; ++it) {
            int j = it * 256 + tid;      // 2048 chunks of 8 f16
            int x = j >> 4, cc = (j & 15) * 8;
            f16x8 v;
            #pragma unroll
            for (int u = 0; u < 8; ++u) v[u] = t[x * 130 + cc + u];
            *(f16x8*)(loiT + (y * HWD + x) * HWD + cc) = v;
        }
    } else if (bid < 640) {
        const int b = bid - 128;         // 0..511
        const float* W = (b < 256) ? W1 : W2;
        f16* Wt = (b < 256) ? W1T : W2T;
        const int bb = b & 255;
        __shared__ f16 t[64 * 66];
        const int k0 = (bb >> 4) * 64;
        const int n0 = (bb & 15) * 64;
        #pragma unroll 4
        for (int it = 0; it < 16; ++it) {
            int i = it * 256 + tid;      // coalesced read over n
            int r = i >> 6, c = i & 63;
            t[c * 66 + r] = (f16)W[(size_t)(k0 + r) * NDIM + n0 + c];
        }
        __syncthreads();
        #pragma unroll
        for (int it = 0; it < 2; ++it) {
            int j = it * 256 + tid;
            int nr = j >> 3, kc = (j & 7) * 8;
            f16x8 v;
            #pragma unroll
            for (int u = 0; u < 8; ++u) v[u] = t[nr * 66 + kc + u];
            const int kk = k0 + kc;      // multiple of 8
            *(f16x8*)(Wt + ((size_t)(kk >> 5) * NDIM + (n0 + nr)) * 32 + (kk & 31)) = v;
        }
    } else if (bid < 704) {
        const int p = (bid - 640) * 256 + tid;   // 64 blocks x 256 = 16384
        const int y = p >> 7, x = p & 127;
        const float c = jloc[p];
        float m = c;
        for (int dy = -1; dy <= 1; ++dy) {
            int yy = y + dy;
            if (yy < 0 || yy >= HWD) continue;
            for (int dx = -1; dx <= 1; ++dx) {
                int xx = x + dx;
                if (xx < 0 || xx >= HWD) continue;
                m = fmaxf(m, jloc[yy * HWD + xx]);
            }
        }
        if (c == m && c > 0.0f) {
            int pos = atomicAdd(count, 1);
            if (pos < MAXCAND) {
                unsigned int ub = __float_as_uint(c);
                cand[pos] = ((unsigned long long)ub << 32) |
                            (unsigned long long)(0xFFFFFFFFu - (unsigned int)p);
            }
        }
    } else {
        const int base = (bid - 704) * 1024 + tid * 4;   // 60 blocks cover 61440
        #pragma unroll
        for (int u = 0; u < 4; ++u)
            if (base + u < out_n) out[base + u] = 0.f;
    }
}

// ---------------------------------------------------------------------------
// Rank-select top-300, LDS-cached. Keys unique => ranks exact; matches
// jax.lax.top_k order (value desc, index asc).
// ---------------------------------------------------------------------------
__global__ __launch_bounds__(256) void rank_junc_kernel(
    const unsigned long long* __restrict__ cand, const int* __restrict__ count,
    const float* __restrict__ joff, float* __restrict__ juncs /* [300][2] */)
{
    __shared__ unsigned long long keys[MAXCAND];   // 32 KB
    const int n = min(*count, MAXCAND);
    const int t = blockIdx.x * 256 + threadIdx.x;  // 16 blocks = 4096 threads
    for (int i = threadIdx.x; i < n; i += 256)
        keys[i] = cand[i];
    __syncthreads();
    if (t >= n) return;
    const unsigned long long key = keys[t];
    int rank = 0;
    int j = 0;
    for (; j + 4 <= n; j += 4) {
        rank += (keys[j]     > key);
        rank += (keys[j + 1] > key);
        rank += (keys[j + 2] > key);
        rank += (keys[j + 3] > key);
    }
    for (; j < n; ++j) rank += (keys[j] > key);
    if (rank < TOPK_N) {
        unsigned int p = 0xFFFFFFFFu - (unsigned int)(key & 0xFFFFFFFFull);
        // x = idx%w + (sigmoid(joff0)-0.5) + 0.5 = idx%w + sigmoid(joff0)
        float sx = 1.0f / (1.0f + expf(-joff[p]));
        float sy = 1.0f / (1.0f + expf(-joff[NPIX + p]));
        juncs[2 * rank + 0] = (float)(p & 127) + sx;
        juncs[2 * rank + 1] = (float)(p >> 7) + sy;
    }
}

// ---------------------------------------------------------------------------
// Per-line sampling, deduplicated: the 4 tap offsets + 4 weights of each of
// the 32 points depend only on the point, not the channel — lanes 0..31
// compute them ONCE into LDS; the channel loop (all 64 lanes, 2 ch each)
// reads them as wave-uniform broadcasts. 4 lines/block (wave per line).
// Output feats in K-chunk-tiled layout (matches GEMM staging).
// ---------------------------------------------------------------------------
__global__ __launch_bounds__(256) void sample_kernel(
    const f16* __restrict__ loiT, const float* __restrict__ juncs,
    const int* __restrict__ edge_idx, f16* __restrict__ feats)
{
    const int wv = threadIdx.x >> 6;
    const int l = blockIdx.x * 4 + wv;
    const int lane = threadIdx.x & 63;

    __shared__ int   soff[4][32][4];   // channel-base element offsets
    __shared__ float swt[4][32][4];    // bilinear weights

    if (lane < 32) {
        const int e0 = edge_idx[2 * l], e1 = edge_idx[2 * l + 1];
        const float ux = juncs[2 * e0], uy = juncs[2 * e0 + 1];
        const float vx = juncs[2 * e1], vy = juncs[2 * e1 + 1];
        const int j = lane;
        const float t = (float)j * (1.0f / 31.0f);
        const float px = ux * t + vx * (1.0f - t) - 0.5f;
        const float py = uy * t + vy * (1.0f - t) - 0.5f;
        float fx0 = fminf(fmaxf(floorf(px), 0.0f), 127.0f);
        float fy0 = fminf(fmaxf(floorf(py), 0.0f), 127.0f);
        float fx1 = fminf(fx0 + 1.0f, 127.0f);
        float fy1 = fminf(fy0 + 1.0f, 127.0f);
        int ix0 = (int)fx0, iy0 = (int)fy0, ix1 = (int)fx1, iy1 = (int)fy1;
        soff[wv][j][0] = (iy0 * HWD + ix0) * HWD;
        soff[wv][j][1] = (iy1 * HWD + ix0) * HWD;
        soff[wv][j][2] = (iy0 * HWD + ix1) * HWD;
        soff[wv][j][3] = (iy1 * HWD + ix1) * HWD;
        swt[wv][j][0] = (fy1 - py) * (fx1 - px);
        swt[wv][j][1] = (py - fy0) * (fx1 - px);
        swt[wv][j][2] = (fy1 - py) * (px - fx0);
        swt[wv][j][3] = (py - fy0) * (px - fx0);
    }
    __syncthreads();

    const int c2 = lane * 2;
    f16x8 o0, o1;
    #pragma unroll
    for (int p = 0; p < 8; ++p) {
        float m0 = -INFINITY, m1 = -INFINITY;
        #pragma unroll
        for (int jj = 0; jj < 4; ++jj) {
            const int j = p * 4 + jj;
            const int b00 = soff[wv][j][0], b10 = soff[wv][j][1];
            const int b01 = soff[wv][j][2], b11 = soff[wv][j][3];
            const float w00 = swt[wv][j][0], w10 = swt[wv][j][1];
            const float w01 = swt[wv][j][2], w11 = swt[wv][j][3];
            f16x2 v00 = *(const f16x2*)(loiT + b00 + c2);
            f16x2 v10 = *(const f16x2*)(loiT + b10 + c2);
            f16x2 v01 = *(const f16x2*)(loiT + b01 + c2);
            f16x2 v11 = *(const f16x2*)(loiT + b11 + c2);
            float s0 = (float)v00.x * w00 + (float)v10.x * w10 +
                       (float)v01.x * w01 + (float)v11.x * w11;
            float s1 = (float)v00.y * w00 + (float)v10.y * w10 +
                       (float)v01.y * w01 + (float)v11.y * w11;
            m0 = fmaxf(m0, s0);
            m1 = fmaxf(m1, s1);
        }
        o0[p] = (f16)m0;   // feature k = 16*lane + p
        o1[p] = (f16)m1;   // feature k = 16*lane + 8 + p
    }
    // tiled: (l, k) -> ((k>>5)*MPAD + l)*32 + (k&31); k-chunk = lane>>1,
    // within-chunk = (lane&1)*16.
    f16* dst = feats + ((size_t)(lane >> 1) * MPAD + l) * 32 + (lane & 1) * 16;
    *(f16x8*)(dst) = o0;
    *(f16x8*)(dst + 8) = o1;
}

// ---------------------------------------------------------------------------
// GEMM: 128x128 tile, 256 threads (2x2 waves of 64x64 subtiles). Two BK=32
// tiles per round (one vmcnt(0)+barrier drain per 32 MFMAs), operands in
// K-chunk-tiled layout (each staged 8KB tile contiguous; G2L = 1KB bursts).
// LDS [row][32] f16 -> proven fragment/bank behavior. Structural floor of
// this family: staged 643MB at ~6 TB/s delivery (R2-R12 sweep).
// head=0: C = relu(A@Bt^T + bias), stored K-chunk-tiled fp16.
// head=1: v = relu(A@Bt^T + bias); out[m][j] += v . W3  (atomicAdd, + b3 once)
// ---------------------------------------------------------------------------
__global__ __launch_bounds__(256, 2) void gemm_bias_relu_kernel(
    const f16* __restrict__ A, const f16* __restrict__ Bt,
    const float* __restrict__ bias, f16* __restrict__ C,
    const float* __restrict__ W3, const float* __restrict__ b3,
    float* __restrict__ out, int K, int head)
{
    const int tid = threadIdx.x;
    const int wave = tid >> 6, lane = tid & 63;
    const int wm = wave >> 1, wn = wave & 1;
    const int m0 = blockIdx.x * 128;
    const int n0 = blockIdx.y * 128;
    const int N = NDIM;

    __shared__ f16 sA0[128 * 32];
    __shared__ f16 sA1[128 * 32];
    __shared__ f16 sB0[128 * 32];
    __shared__ f16 sB1[128 * 32];

    f32x4 acc[4][4];
    #pragma unroll
    for (int mi = 0; mi < 4; ++mi)
        #pragma unroll
        for (int ni = 0; ni < 4; ++ni)
            acc[mi][ni] = (f32x4){0.f, 0.f, 0.f, 0.f};

    // Tiled staging: chunk c of A-tile = contiguous 4096 f16 at
    // A + (c*MPAD + m0)*32. Wave w stages segs {w, w+4} (1KB each);
    // lane i deposits/fetches seg_base + i*16B. Global == LDS order.
    const size_t strideA = (size_t)MPAD * 32;   // f16 per k-chunk
    const size_t strideB = (size_t)NDIM * 32;
    const f16* gA = A + (size_t)m0 * 32 + wave * 512 + lane * 8;
    const f16* gB = Bt + (size_t)n0 * 32 + wave * 512 + lane * 8;
    const int so0 = wave * 512;                 // + lane*16B implicit
    const int so1 = (wave + 4) * 512;

    const int col16 = lane & 15;
    const int kq = (lane >> 4) * 8;

    const int NC = K >> 5;                      // 32 k-chunks
    for (int c0 = 0; c0 < NC; c0 += 2) {
        const f16* a0 = gA + (size_t)c0 * strideA;
        const f16* a1 = a0 + strideA;
        const f16* b0 = gB + (size_t)c0 * strideB;
        const f16* b1 = b0 + strideB;
        __syncthreads();                      // prev round's LDS reads complete
        G2L(a0, sA0 + so0);
        G2L(a0 + 2048, sA0 + so1);
        G2L(b0, sB0 + so0);
        G2L(b0 + 2048, sB0 + so1);
        G2L(a1, sA1 + so0);
        G2L(a1 + 2048, sA1 + so1);
        G2L(b1, sB1 + so0);
        G2L(b1 + 2048, sB1 + so1);
        __builtin_amdgcn_s_waitcnt(0x0f70);   // vmcnt(0): own DMA done
        __syncthreads();                      // all waves' DMA done

        {
            f16x8 af[4], bf[4];
            #pragma unroll
            for (int i = 0; i < 4; ++i) {
                af[i] = *(const f16x8*)(sA0 + (wm * 64 + i * 16 + col16) * 32 + kq);
                bf[i] = *(const f16x8*)(sB0 + (wn * 64 + i * 16 + col16) * 32 + kq);
            }
            #pragma unroll
            for (int mi = 0; mi < 4; ++mi)
                #pragma unroll
                for (int ni = 0; ni < 4; ++ni)
                    acc[mi][ni] = __builtin_amdgcn_mfma_f32_16x16x32_f16(
                        af[mi], bf[ni], acc[mi][ni], 0, 0, 0);
        }
        {
            f16x8 af[4], bf[4];
            #pragma unroll
            for (int i = 0; i < 4; ++i) {
                af[i] = *(const f16x8*)(sA1 + (wm * 64 + i * 16 + col16) * 32 + kq);
                bf[i] = *(const f16x8*)(sB1 + (wn * 64 + i * 16 + col16) * 32 + kq);
            }
            #pragma unroll
            for (int mi = 0; mi < 4; ++mi)
                #pragma unroll
                for (int ni = 0; ni < 4; ++ni)
                    acc[mi][ni] = __builtin_amdgcn_mfma_f32_16x16x32_f16(
                        af[mi], bf[ni], acc[mi][ni], 0, 0, 0);
        }
    }

    const int quad = lane >> 4;
    if (!head) {
        #pragma unroll
        for (int ni = 0; ni < 4; ++ni) {
            const int n = n0 + wn * 64 + ni * 16 + col16;
            const float b = bias[n];
            const size_t cb = ((size_t)(n >> 5) * MPAD) * 32 + (n & 31);
            #pragma unroll
            for (int mi = 0; mi < 4; ++mi) {
                #pragma unroll
                for (int r = 0; r < 4; ++r) {
                    const int m = m0 + wm * 64 + mi * 16 + quad * 4 + r;
                    float v = fmaxf(acc[mi][ni][r] + b, 0.f);
                    C[cb + (size_t)m * 32] = (f16)v;   // K-chunk-tiled
                }
            }
        }
    } else {
        float bb[4], w3c[4][3];
        #pragma unroll
        for (int ni = 0; ni < 4; ++ni) {
            const int n = n0 + wn * 64 + ni * 16 + col16;
            bb[ni] = bias[n];
            #pragma unroll
            for (int jj = 0; jj < 3; ++jj) w3c[ni][jj] = W3[n * 3 + jj];
        }
        const bool addb3 = (blockIdx.y == 0 && wn == 0);
        #pragma unroll
        for (int mi = 0; mi < 4; ++mi) {
            #pragma unroll
            for (int r = 0; r < 4; ++r) {
                float s0 = 0.f, s1 = 0.f, s2 = 0.f;
                #pragma unroll
                for (int ni = 0; ni < 4; ++ni) {
                    float v = fmaxf(acc[mi][ni][r] + bb[ni], 0.f);
                    s0 += v * w3c[ni][0];
                    s1 += v * w3c[ni][1];
                    s2 += v * w3c[ni][2];
                }
                #pragma unroll
                for (int mask = 1; mask <= 8; mask <<= 1) {
                    s0 += __shfl_xor(s0, mask);
                    s1 += __shfl_xor(s1, mask);
                    s2 += __shfl_xor(s2, mask);
                }
                if (col16 == 0) {
                    const int m = m0 + wm * 64 + mi * 16 + quad * 4 + r;
                    if (m < NLINES) {
                        atomicAdd(&out[m * 3 + 0], s0 + (addb3 ? b3[0] : 0.f));
                        atomicAdd(&out[m * 3 + 1], s1 + (addb3 ? b3[1] : 0.f));
                        atomicAdd(&out[m * 3 + 2], s2 + (addb3 ? b3[2] : 0.f));
                    }
                }
            }
        }
    }
}

// ---------------------------------------------------------------------------
extern "C" void kernel_launch(void* const* d_in, const int* in_sizes, int n_in,
                              void* d_out, int out_size, void* d_ws, size_t ws_size,
                              hipStream_t stream)
{
    const float* jloc = (const float*)d_in[0];
    const float* joff = (const float*)d_in[1];
    const float* loi  = (const float*)d_in[2];
    const int*   eidx = (const int*)d_in[3];
    const float* W1   = (const float*)d_in[4];
    const float* b1   = (const float*)d_in[5];
    const float* W2   = (const float*)d_in[6];
    const float* b2   = (const float*)d_in[7];
    const float* W3   = (const float*)d_in[8];
    const float* b3   = (const float*)d_in[9];
    float* out = (float*)d_out;

    char* ws = (char*)d_ws;
    f16*   loiT  = (f16*)(ws);                            // 4 MB
    f16*   W1T   = (f16*)(ws + ((size_t)4 << 20));        // 2 MB
    f16*   W2T   = (f16*)(ws + ((size_t)6 << 20));        // 2 MB
    float* juncs = (float*)(ws + ((size_t)8 << 20));      // 2.4 KB
    int*   count = (int*)(ws + ((size_t)8 << 20) + 4096);
    unsigned long long* cand =
        (unsigned long long*)(ws + ((size_t)8 << 20) + 8192);  // 32 KB
    f16*   feats = (f16*)(ws + ((size_t)9 << 20));        // 40 MB (tiled MPADx1024)
    f16*   h1    = (f16*)(ws + ((size_t)51 << 20));       // 40 MB (tiled)

    hipMemsetAsync(count, 0, sizeof(int), stream);
    preproc_kernel<<<dim3(764), dim3(256), 0, stream>>>(
        loi, loiT, W1, W1T, W2, W2T, jloc, cand, count, out, out_size);
    rank_junc_kernel<<<dim3(MAXCAND / 256), dim3(256), 0, stream>>>(
        cand, count, joff, juncs);
    sample_kernel<<<dim3(NLINES / 4), dim3(256), 0, stream>>>(loiT, juncs, eidx, feats);
    gemm_bias_relu_kernel<<<dim3(MPAD / 128, NDIM / 128), dim3(256), 0, stream>>>(
        feats, W1T, b1, h1, nullptr, nullptr, nullptr, KDIM, 0);
    gemm_bias_relu_kernel<<<dim3(MPAD / 128, NDIM / 128), dim3(256), 0, stream>>>(
        h1, W2T, b2, nullptr, W3, b3, out, KDIM, 1);
}